// Round 10
// baseline (120.709 us; speedup 1.0000x reference)
//
#include <hip/hip_runtime.h>

// Problem constants (from reference)
#define TOK_CODE_START 256
#define TOK_CODE_END   257
#define TOK_MEM        258
#define ADDR_KEY       206
#define MEM_STORE      455

constexpr int Bb = 16;
constexpr int Ss = 8192;
constexpr int DM = 512;

typedef float f32x4 __attribute__((ext_vector_type(4)));

// ---------------------------------------------------------------------------
// Kernel 1: per-row scan. One block per batch row, 1024 threads (16 waves),
// 8 tokens per thread. Wave-level shuffle scan + one LDS round for the 16
// wave carries. Packs per (b,s):
//   bits[0..8]=token  bit9=valid  bit10=mem_flag  bits[11..]=addr
// into one u32 in d_ws.  (unchanged since R3)
// ---------------------------------------------------------------------------
__global__ __launch_bounds__(1024) void vm_scan_kernel(
    const int* __restrict__ tok,
    const int* __restrict__ mhe_p,
    unsigned int* __restrict__ ws)
{
    const int b = blockIdx.x;
    const int t = threadIdx.x;              // 0..1023
    const int lane = t & 63;
    const int wid = t >> 6;                 // 0..15
    const int mhe = mhe_p[0];
    const int* row = tok + b * Ss;
    const int base = t * 8;

    int toks[8];
    int4 v0 = reinterpret_cast<const int4*>(row + base)[0];
    int4 v1 = reinterpret_cast<const int4*>(row + base)[1];
    toks[0] = v0.x; toks[1] = v0.y; toks[2] = v0.z; toks[3] = v0.w;
    toks[4] = v1.x; toks[5] = v1.y; toks[6] = v1.z; toks[7] = v1.w;

    // per-thread chunk summaries
    int lmax = -1;      // max index of CODE_START in my 8 (-1 if none)
    int lend = Ss;      // first index of CODE_END in my 8 (Ss if none)
    #pragma unroll
    for (int k = 0; k < 8; ++k) {
        int idx = base + k;
        if (toks[k] == TOK_CODE_START) lmax = idx;             // idx increasing
        if (toks[k] == TOK_CODE_END && lend == Ss) lend = idx; // first
    }

    // wave inclusive max-scan of lmax (6 shuffle steps, no barriers)
    #pragma unroll
    for (int off = 1; off < 64; off <<= 1) {
        int u = __shfl_up(lmax, off);
        if (lane >= off && u > lmax) lmax = u;
    }
    // exclusive version for this thread
    int excl = __shfl_up(lmax, 1);
    if (lane == 0) excl = -1;

    // wave min-reduce of lend (all lanes get the wave min)
    #pragma unroll
    for (int off = 32; off > 0; off >>= 1) {
        int u = __shfl_xor(lend, off);
        if (u < lend) lend = u;
    }

    __shared__ int wmax[16];   // per-wave inclusive total (lane 63's value)
    __shared__ int wend[16];   // per-wave min first-end
    if (lane == 63) wmax[wid] = lmax;
    if (lane == 0)  wend[wid] = lend;
    __syncthreads();

    int carry = -1;
    #pragma unroll
    for (int j = 0; j < 16; ++j)
        if (j < wid && wmax[j] > carry) carry = wmax[j];
    int end_idx = Ss;
    #pragma unroll
    for (int j = 0; j < 16; ++j)
        if (wend[j] < end_idx) end_idx = wend[j];

    int run = (carry > excl) ? carry : excl;   // latest start strictly before my chunk

    unsigned int pk[8];
    #pragma unroll
    for (int k = 0; k < 8; ++k) {
        int idx = base + k;
        int tv = toks[k];
        if (tv == TOK_CODE_START) run = idx;   // inclusive cummax update
        int cs = run;
        int addr = idx - cs - 1;
        bool valid = (cs >= 0) && (idx < end_idx) && (tv < 256) && (addr >= 0);
        bool memf  = (tv == TOK_MEM) && (idx < mhe);
        unsigned int w = (unsigned int)tv;                       // bits 0..8
        if (valid) w |= (1u << 9) | ((unsigned int)addr << 11);
        if (memf)  w |= (1u << 10);
        pk[k] = w;
    }
    uint4* wr = reinterpret_cast<uint4*>(ws + b * Ss + base);
    wr[0] = make_uint4(pk[0], pk[1], pk[2], pk[3]);
    wr[1] = make_uint4(pk[4], pk[5], pk[6], pk[7]);
}

// ---------------------------------------------------------------------------
// Kernel 2: gather + mask overwrite, grid-stride, nt stores.
// SINGLE CHANGE vs R3 champion (51.4 us): 32 BYTES per work item (2 adjacent
// float4 quads). One ws load + one address calc + one mask evaluation now
// serves 32 B of output instead of 16 B — halves per-byte instruction
// overhead. Plain loop, no manual batching (R9 lesson: let the compiler
// schedule the loads).
// ---------------------------------------------------------------------------
__global__ __launch_bounds__(256) void vm_gather_kernel(
    const f32x4* __restrict__ emb,
    const unsigned int* __restrict__ ws,
    f32x4* __restrict__ out)
{
    const int total = Bb * Ss * (DM / 8);    // 8,388,608 pairs of quads
    const int stride = gridDim.x * blockDim.x;
    for (int p = blockIdx.x * blockDim.x + threadIdx.x; p < total; p += stride) {
        int bs = p >> 6;                     // 64 pairs per (b,s)
        int dp = p & 63;                     // pair index: dims [dp*8, dp*8+8)
        unsigned int pw = ws[bs];
        int tk = (int)(pw & 511u);
        int ebase = tk * (DM / 4) + dp * 2;
        f32x4 va = emb[ebase];
        f32x4 vb = emb[ebase + 1];
        unsigned int flags = pw >> 9;
        if (flags) {                         // ~wave-uniform branch, mostly false
            bool valid = (flags & 1u) != 0u;
            bool memf  = (flags & 2u) != 0u;
            int addr = (int)(flags >> 2);
            int p0 = ADDR_KEY      + (addr & 15);
            int p1 = ADDR_KEY + 16 + ((addr >> 4) & 15);
            int p2 = ADDR_KEY + 32 + ((addr >> 8) & 15);
            int d0 = dp << 3;
            #pragma unroll
            for (int j = 0; j < 4; ++j) {
                int d = d0 + j;
                if ((valid && (d == p0 || d == p1 || d == p2)) ||
                    (memf && d == MEM_STORE)) va[j] = 1.0f;
            }
            #pragma unroll
            for (int j = 0; j < 4; ++j) {
                int d = d0 + 4 + j;
                if ((valid && (d == p0 || d == p1 || d == p2)) ||
                    (memf && d == MEM_STORE)) vb[j] = 1.0f;
            }
        }
        __builtin_nontemporal_store(va, &out[p * 2]);
        __builtin_nontemporal_store(vb, &out[p * 2 + 1]);
    }
}

extern "C" void kernel_launch(void* const* d_in, const int* in_sizes, int n_in,
                              void* d_out, int out_size, void* d_ws, size_t ws_size,
                              hipStream_t stream) {
    const int* tok = (const int*)d_in[0];
    const float* emb = (const float*)d_in[1];
    const int* mhe = (const int*)d_in[2];
    unsigned int* ws = (unsigned int*)d_ws;   // needs Bb*Ss*4 = 512 KiB
    f32x4* out = (f32x4*)d_out;

    vm_scan_kernel<<<Bb, 1024, 0, stream>>>(tok, mhe, ws);
    vm_gather_kernel<<<2048, 256, 0, stream>>>((const f32x4*)emb, ws, out);
}

// Round 11
// 56.535 us; speedup vs baseline: 2.1351x; 2.1351x over previous
//
#include <hip/hip_runtime.h>

// Problem constants (from reference)
#define TOK_CODE_START 256
#define TOK_CODE_END   257
#define TOK_MEM        258
#define ADDR_KEY       206
#define MEM_STORE      455

constexpr int Bb = 16;
constexpr int Ss = 8192;
constexpr int DM = 512;

typedef float f32x4 __attribute__((ext_vector_type(4)));

// ---------------------------------------------------------------------------
// Kernel 1: per-row scan. One block per batch row, 1024 threads (16 waves),
// 8 tokens per thread. Wave-level shuffle scan + one LDS round for the 16
// wave carries. Packs per (b,s):
//   bits[0..8]=token  bit9=valid  bit10=mem_flag  bits[11..]=addr
// into one u32 in d_ws.  (unchanged since R3)
// ---------------------------------------------------------------------------
__global__ __launch_bounds__(1024) void vm_scan_kernel(
    const int* __restrict__ tok,
    const int* __restrict__ mhe_p,
    unsigned int* __restrict__ ws)
{
    const int b = blockIdx.x;
    const int t = threadIdx.x;              // 0..1023
    const int lane = t & 63;
    const int wid = t >> 6;                 // 0..15
    const int mhe = mhe_p[0];
    const int* row = tok + b * Ss;
    const int base = t * 8;

    int toks[8];
    int4 v0 = reinterpret_cast<const int4*>(row + base)[0];
    int4 v1 = reinterpret_cast<const int4*>(row + base)[1];
    toks[0] = v0.x; toks[1] = v0.y; toks[2] = v0.z; toks[3] = v0.w;
    toks[4] = v1.x; toks[5] = v1.y; toks[6] = v1.z; toks[7] = v1.w;

    // per-thread chunk summaries
    int lmax = -1;      // max index of CODE_START in my 8 (-1 if none)
    int lend = Ss;      // first index of CODE_END in my 8 (Ss if none)
    #pragma unroll
    for (int k = 0; k < 8; ++k) {
        int idx = base + k;
        if (toks[k] == TOK_CODE_START) lmax = idx;             // idx increasing
        if (toks[k] == TOK_CODE_END && lend == Ss) lend = idx; // first
    }

    // wave inclusive max-scan of lmax (6 shuffle steps, no barriers)
    #pragma unroll
    for (int off = 1; off < 64; off <<= 1) {
        int u = __shfl_up(lmax, off);
        if (lane >= off && u > lmax) lmax = u;
    }
    // exclusive version for this thread
    int excl = __shfl_up(lmax, 1);
    if (lane == 0) excl = -1;

    // wave min-reduce of lend (all lanes get the wave min)
    #pragma unroll
    for (int off = 32; off > 0; off >>= 1) {
        int u = __shfl_xor(lend, off);
        if (u < lend) lend = u;
    }

    __shared__ int wmax[16];   // per-wave inclusive total (lane 63's value)
    __shared__ int wend[16];   // per-wave min first-end
    if (lane == 63) wmax[wid] = lmax;
    if (lane == 0)  wend[wid] = lend;
    __syncthreads();

    int carry = -1;
    #pragma unroll
    for (int j = 0; j < 16; ++j)
        if (j < wid && wmax[j] > carry) carry = wmax[j];
    int end_idx = Ss;
    #pragma unroll
    for (int j = 0; j < 16; ++j)
        if (wend[j] < end_idx) end_idx = wend[j];

    int run = (carry > excl) ? carry : excl;   // latest start strictly before my chunk

    unsigned int pk[8];
    #pragma unroll
    for (int k = 0; k < 8; ++k) {
        int idx = base + k;
        int tv = toks[k];
        if (tv == TOK_CODE_START) run = idx;   // inclusive cummax update
        int cs = run;
        int addr = idx - cs - 1;
        bool valid = (cs >= 0) && (idx < end_idx) && (tv < 256) && (addr >= 0);
        bool memf  = (tv == TOK_MEM) && (idx < mhe);
        unsigned int w = (unsigned int)tv;                       // bits 0..8
        if (valid) w |= (1u << 9) | ((unsigned int)addr << 11);
        if (memf)  w |= (1u << 10);
        pk[k] = w;
    }
    uint4* wr = reinterpret_cast<uint4*>(ws + b * Ss + base);
    wr[0] = make_uint4(pk[0], pk[1], pk[2], pk[3]);
    wr[1] = make_uint4(pk[4], pk[5], pk[6], pk[7]);
}

// ---------------------------------------------------------------------------
// Kernel 2: gather + mask overwrite, grid-stride, nt stores.
// 32 B per thread, WAVE-STRIDE pair layout (fix of R10's coalescing bug):
// thread handles quads (bs*128 + dq) and (bs*128 + dq + 64) of the SAME
// (b,s). Per wave: one broadcast ws word, two fully-contiguous 1024 B
// store segments, two contiguous embed load segments. Plain loop — the
// compiler schedules the loads (R9 lesson).
// ---------------------------------------------------------------------------
__global__ __launch_bounds__(256) void vm_gather_kernel(
    const f32x4* __restrict__ emb,
    const unsigned int* __restrict__ ws,
    f32x4* __restrict__ out)
{
    const int total = Bb * Ss * 64;          // 8,388,608 pair-items
    const int stride = gridDim.x * blockDim.x;
    for (int p = blockIdx.x * blockDim.x + threadIdx.x; p < total; p += stride) {
        int bs = p >> 6;                     // 64 pair-items per (b,s)
        int dq = p & 63;                     // quad indices dq and dq+64
        unsigned int pw = ws[bs];            // wave-uniform (whole wave: same bs)
        int tk = (int)(pw & 511u);
        int ebase = tk * (DM / 4);
        f32x4 va = emb[ebase + dq];
        f32x4 vb = emb[ebase + dq + 64];
        unsigned int flags = pw >> 9;
        if (flags) {                         // wave-uniform branch, mostly false
            bool valid = (flags & 1u) != 0u;
            bool memf  = (flags & 2u) != 0u;
            int addr = (int)(flags >> 2);
            int p0 = ADDR_KEY      + (addr & 15);
            int p1 = ADDR_KEY + 16 + ((addr >> 4) & 15);
            int p2 = ADDR_KEY + 32 + ((addr >> 8) & 15);
            int d0 = dq << 2;                // dims of va: d0..d0+3
            #pragma unroll
            for (int j = 0; j < 4; ++j) {
                int d = d0 + j;
                if ((valid && (d == p0 || d == p1 || d == p2)) ||
                    (memf && d == MEM_STORE)) va[j] = 1.0f;
            }
            #pragma unroll
            for (int j = 0; j < 4; ++j) {
                int d = d0 + 256 + j;        // dims of vb: d0+256..d0+259
                if ((valid && (d == p0 || d == p1 || d == p2)) ||
                    (memf && d == MEM_STORE)) vb[j] = 1.0f;
            }
        }
        int obase = bs * 128 + dq;
        __builtin_nontemporal_store(va, &out[obase]);
        __builtin_nontemporal_store(vb, &out[obase + 64]);
    }
}

extern "C" void kernel_launch(void* const* d_in, const int* in_sizes, int n_in,
                              void* d_out, int out_size, void* d_ws, size_t ws_size,
                              hipStream_t stream) {
    const int* tok = (const int*)d_in[0];
    const float* emb = (const float*)d_in[1];
    const int* mhe = (const int*)d_in[2];
    unsigned int* ws = (unsigned int*)d_ws;   // needs Bb*Ss*4 = 512 KiB
    f32x4* out = (f32x4*)d_out;

    vm_scan_kernel<<<Bb, 1024, 0, stream>>>(tok, mhe, ws);
    vm_gather_kernel<<<2048, 256, 0, stream>>>((const f32x4*)emb, ws, out);
}